// Round 5
// baseline (41.241 us; speedup 1.0000x reference)
//
#include <hip/hip_runtime.h>

// Problem geometry (fixed by the reference):
//   embeddings: (8, 2048, 768) fp32
//   W: (1536,) fp32  -> W_left = W[:768], W_right = W[768:]
//   b: (1,) fp32
//   out[b,i,j] = dot(emb[b,i,:], W_left) + dot(emb[b,j,:], W_right) + b[0]
#define PB_H 768
#define PB_L 2048
#define PB_B 8
#define PB_ROWS (PB_B * PB_L)   // 16384

typedef float f4x __attribute__((ext_vector_type(4)));

// Kernel 1: per-row dual dot product, 2 rows per wave, all loads issued
// up-front (6 outstanding 16B loads/lane = more MLP than the 3-load
// version). 2048 blocks x 4 waves x 2 rows = 16384 rows.
__global__ void probe_dot_kernel(const float* __restrict__ emb,
                                 const float* __restrict__ W,
                                 const float* __restrict__ bptr,
                                 float* __restrict__ left,
                                 float* __restrict__ right) {
    const int wave = threadIdx.x >> 6;
    const int lane = threadIdx.x & 63;
    const int row0 = ((blockIdx.x << 2) + wave) << 1;   // first of 2 rows

    const f4x* e0p = reinterpret_cast<const f4x*>(emb + (size_t)row0 * PB_H);
    const f4x* e1p = reinterpret_cast<const f4x*>(emb + (size_t)(row0 + 1) * PB_H);
    const f4x* wl  = reinterpret_cast<const f4x*>(W);
    const f4x* wr  = reinterpret_cast<const f4x*>(W + PB_H);

    // Issue all 6 embedding loads (nontemporal: streamed) + 6 W loads (cached)
    f4x a0 = __builtin_nontemporal_load(&e0p[lane]);
    f4x a1 = __builtin_nontemporal_load(&e0p[64 + lane]);
    f4x a2 = __builtin_nontemporal_load(&e0p[128 + lane]);
    f4x b0 = __builtin_nontemporal_load(&e1p[lane]);
    f4x b1 = __builtin_nontemporal_load(&e1p[64 + lane]);
    f4x b2 = __builtin_nontemporal_load(&e1p[128 + lane]);
    f4x l0 = wl[lane], l1 = wl[64 + lane], l2 = wl[128 + lane];
    f4x r0 = wr[lane], r1 = wr[64 + lane], r2 = wr[128 + lane];

    float aL = a0.x*l0.x + a0.y*l0.y + a0.z*l0.z + a0.w*l0.w
             + a1.x*l1.x + a1.y*l1.y + a1.z*l1.z + a1.w*l1.w
             + a2.x*l2.x + a2.y*l2.y + a2.z*l2.z + a2.w*l2.w;
    float aR = a0.x*r0.x + a0.y*r0.y + a0.z*r0.z + a0.w*r0.w
             + a1.x*r1.x + a1.y*r1.y + a1.z*r1.z + a1.w*r1.w
             + a2.x*r2.x + a2.y*r2.y + a2.z*r2.z + a2.w*r2.w;
    float bL = b0.x*l0.x + b0.y*l0.y + b0.z*l0.z + b0.w*l0.w
             + b1.x*l1.x + b1.y*l1.y + b1.z*l1.z + b1.w*l1.w
             + b2.x*l2.x + b2.y*l2.y + b2.z*l2.z + b2.w*l2.w;
    float bR = b0.x*r0.x + b0.y*r0.y + b0.z*r0.z + b0.w*r0.w
             + b1.x*r1.x + b1.y*r1.y + b1.z*r1.z + b1.w*r1.w
             + b2.x*r2.x + b2.y*r2.y + b2.z*r2.z + b2.w*r2.w;

#pragma unroll
    for (int off = 32; off >= 1; off >>= 1) {
        aL += __shfl_xor(aL, off);
        aR += __shfl_xor(aR, off);
        bL += __shfl_xor(bL, off);
        bR += __shfl_xor(bR, off);
    }

    if (lane == 0) {
        const float bias = bptr[0];
        left[row0]      = aL + bias;
        right[row0]     = aR;
        left[row0 + 1]  = bL + bias;
        right[row0 + 1] = bR;
    }
}

// Kernel 2: broadcast add, fill-kernel style: 2048 blocks x 256 threads,
// grid-stride, 16 float4 NT stores per thread. Within a wave t is
// contiguous -> row = t>>9 is wave-uniform, stores are 1 KiB coalesced.
#define K2_BLOCKS 2048
#define K2_THREADS 256
#define K2_TOTAL (K2_BLOCKS * K2_THREADS)            // 524288
#define OUT_F4 (PB_ROWS * (PB_L / 4))                // 8388608
#define K2_ITERS (OUT_F4 / K2_TOTAL)                 // 16

__global__ void __launch_bounds__(K2_THREADS)
probe_bcast_kernel(const float* __restrict__ left,
                   const float* __restrict__ right,
                   f4x* __restrict__ out) {
    const int tid = blockIdx.x * K2_THREADS + threadIdx.x;
#pragma unroll
    for (int it = 0; it < K2_ITERS; ++it) {
        const int t   = tid + it * K2_TOTAL;         // < 2^23, int ok
        const int j4  = t & 511;
        const int row = t >> 9;                      // wave-uniform
        const int b   = row >> 11;

        const float lv = left[row];
        f4x rv = reinterpret_cast<const f4x*>(right + ((size_t)b << 11))[j4];
        f4x o = rv + lv;
        __builtin_nontemporal_store(o, &out[(size_t)t]);
    }
}

extern "C" void kernel_launch(void* const* d_in, const int* in_sizes, int n_in,
                              void* d_out, int out_size, void* d_ws, size_t ws_size,
                              hipStream_t stream) {
    const float* emb  = (const float*)d_in[0];
    const float* W    = (const float*)d_in[1];
    const float* bias = (const float*)d_in[2];
    f4x* out = (f4x*)d_out;

    float* left  = (float*)d_ws;            // 16384 floats
    float* right = left + PB_ROWS;          // 16384 floats (128 KiB total)

    // Kernel 1: 16384 rows / (4 waves * 2 rows) = 2048 blocks
    probe_dot_kernel<<<2048, 256, 0, stream>>>(emb, W, bias, left, right);

    // Kernel 2: fill-style grid-stride
    probe_bcast_kernel<<<K2_BLOCKS, K2_THREADS, 0, stream>>>(left, right, out);
}

// Round 6
// 35.260 us; speedup vs baseline: 1.1696x; 1.1696x over previous
//
#include <hip/hip_runtime.h>

// Problem geometry (fixed by the reference):
//   embeddings: (8, 2048, 768) fp32
//   W: (1536,) fp32  -> W_left = W[:768], W_right = W[768:]
//   b: (1,) fp32
//   out[b,i,j] = dot(emb[b,i,:], W_left) + dot(emb[b,j,:], W_right) + b[0]
#define PB_H 768
#define PB_L 2048
#define PB_B 8
#define PB_ROWS (PB_B * PB_L)   // 16384

typedef float f4x __attribute__((ext_vector_type(4)));

// Kernel 1: per-row dual dot product.
// One wave (64 lanes) per row; 4 waves per 256-thread block; 4096 blocks.
// Lane k reads float4s at offsets {0,64,128}+k -> three 1 KiB wave loads.
// Loads are CACHED (no NT): embeddings are 48 MiB and L3-resident across
// graph replays as long as nothing evicts them (k2 stores are NT).
__global__ void probe_dot_kernel(const float* __restrict__ emb,
                                 const float* __restrict__ W,
                                 const float* __restrict__ bptr,
                                 float* __restrict__ left,
                                 float* __restrict__ right) {
    const int wave = threadIdx.x >> 6;
    const int lane = threadIdx.x & 63;
    const int row  = (blockIdx.x << 2) + wave;          // [0, 16384)

    const f4x* e  = reinterpret_cast<const f4x*>(emb + (size_t)row * PB_H);
    const f4x* wl = reinterpret_cast<const f4x*>(W);
    const f4x* wr = reinterpret_cast<const f4x*>(W + PB_H);

    float accl = 0.f, accr = 0.f;
#pragma unroll
    for (int k = 0; k < 3; ++k) {
        const int idx = k * 64 + lane;                  // float4 index within row
        f4x ev = e[idx];                                // cached load
        f4x lv = wl[idx];
        f4x rv = wr[idx];
        accl += ev.x * lv.x + ev.y * lv.y + ev.z * lv.z + ev.w * lv.w;
        accr += ev.x * rv.x + ev.y * rv.y + ev.z * rv.z + ev.w * rv.w;
    }

    // 64-lane butterfly reduction
#pragma unroll
    for (int off = 32; off >= 1; off >>= 1) {
        accl += __shfl_xor(accl, off);
        accr += __shfl_xor(accr, off);
    }

    if (lane == 0) {
        left[row]  = accl + bptr[0];   // fold bias into left
        right[row] = accr;
    }
}

// Kernel 2: broadcast add. One block per output row (b,i); 256 threads,
// 2 float4 each. left[row] is blockIdx-uniform -> scalar load. right
// chunk reads are 1 KiB coalesced and L2-resident (64 KiB total).
// Output stores NONTEMPORAL: write-once data must not evict the
// embeddings from L3 (k1 depends on their residency across replays).
__global__ void probe_bcast_kernel(const float* __restrict__ left,
                                   const float* __restrict__ right,
                                   f4x* __restrict__ out) {
    const int row = blockIdx.x;             // b*2048 + i
    const int b   = row >> 11;
    const float lv = left[row];             // uniform scalar load

    const f4x* rrow = reinterpret_cast<const f4x*>(right + ((size_t)b << 11));
    f4x* orow = out + ((size_t)row << 9);   // 512 float4 per row

#pragma unroll
    for (int k = 0; k < 2; ++k) {
        const int j4 = threadIdx.x + (k << 8);
        f4x rv = rrow[j4];
        f4x o = rv + lv;
        __builtin_nontemporal_store(o, &orow[j4]);
    }
}

extern "C" void kernel_launch(void* const* d_in, const int* in_sizes, int n_in,
                              void* d_out, int out_size, void* d_ws, size_t ws_size,
                              hipStream_t stream) {
    const float* emb  = (const float*)d_in[0];
    const float* W    = (const float*)d_in[1];
    const float* bias = (const float*)d_in[2];
    f4x* out = (f4x*)d_out;

    float* left  = (float*)d_ws;            // 16384 floats
    float* right = left + PB_ROWS;          // 16384 floats (128 KiB total)

    // Kernel 1: 16384 rows / 4 waves per block = 4096 blocks
    probe_dot_kernel<<<4096, 256, 0, stream>>>(emb, W, bias, left, right);

    // Kernel 2: one block per output row
    probe_bcast_kernel<<<PB_ROWS, 256, 0, stream>>>(left, right, out);
}

// Round 7
// 33.584 us; speedup vs baseline: 1.2280x; 1.0499x over previous
//
#include <hip/hip_runtime.h>

// Problem geometry (fixed by the reference):
//   embeddings: (8, 2048, 768) fp32
//   W: (1536,) fp32  -> W_left = W[:768], W_right = W[768:]
//   b: (1,) fp32
//   out[b,i,j] = dot(emb[b,i,:], W_left) + dot(emb[b,j,:], W_right) + b[0]
//
// Structure (settled over rounds 1-6):
//   - Two dispatches. k1: 48 MiB streaming read + dual dot; k2: 128 MiB
//     streaming write. Both BW-bound; total 34.7 us vs ~31-33 us
//     overhead-inclusive floor.
//   - Cooperative single-kernel fusion: 3.7x WORSE (grid sync + capped
//     co-residency collapse BW). Narrow-grid deep-loop k2: +6.3 us.
//     NT-vs-cached on either kernel: null. Wide grid is what matters.
#define PB_H 768
#define PB_L 2048
#define PB_B 8
#define PB_ROWS (PB_B * PB_L)   // 16384

typedef float f4x __attribute__((ext_vector_type(4)));

// Kernel 1: per-row dual dot product.
// One wave (64 lanes) per row; 4 waves per 256-thread block; 4096 blocks.
// Lane k reads float4s at offsets {0,64,128}+k -> three 1 KiB wave loads.
__global__ void probe_dot_kernel(const float* __restrict__ emb,
                                 const float* __restrict__ W,
                                 const float* __restrict__ bptr,
                                 float* __restrict__ left,
                                 float* __restrict__ right) {
    const int wave = threadIdx.x >> 6;
    const int lane = threadIdx.x & 63;
    const int row  = (blockIdx.x << 2) + wave;          // [0, 16384)

    const f4x* e  = reinterpret_cast<const f4x*>(emb + (size_t)row * PB_H);
    const f4x* wl = reinterpret_cast<const f4x*>(W);
    const f4x* wr = reinterpret_cast<const f4x*>(W + PB_H);

    float accl = 0.f, accr = 0.f;
#pragma unroll
    for (int k = 0; k < 3; ++k) {
        const int idx = k * 64 + lane;                  // float4 index within row
        f4x ev = e[idx];
        f4x lv = wl[idx];
        f4x rv = wr[idx];
        accl += ev.x * lv.x + ev.y * lv.y + ev.z * lv.z + ev.w * lv.w;
        accr += ev.x * rv.x + ev.y * rv.y + ev.z * rv.z + ev.w * rv.w;
    }

    // 64-lane butterfly reduction
#pragma unroll
    for (int off = 32; off >= 1; off >>= 1) {
        accl += __shfl_xor(accl, off);
        accr += __shfl_xor(accr, off);
    }

    if (lane == 0) {
        left[row]  = accl + bptr[0];   // fold bias into left
        right[row] = accr;
    }
}

// Kernel 2: broadcast add. Wide grid (32768 blocks), one float4 per
// thread — the best-measured store structure. Within a wave t is
// contiguous -> row (= t>>9) is wave-uniform; stores are 1 KiB
// coalesced. right chunk (8 KiB/batch) is L2-resident.
__global__ void probe_bcast_kernel(const float* __restrict__ left,
                                   const float* __restrict__ right,
                                   f4x* __restrict__ out) {
    const long long t = (long long)blockIdx.x * blockDim.x + threadIdx.x;
    const int j4  = (int)(t & 511);         // 2048/4 = 512 float4 per row
    const int row = (int)(t >> 9);          // b*2048 + i
    const int b   = row >> 11;

    const float lv = left[row];
    const f4x rv = reinterpret_cast<const f4x*>(right + ((size_t)b << 11))[j4];
    f4x o = rv + lv;
    __builtin_nontemporal_store(o, &out[t]);
}

extern "C" void kernel_launch(void* const* d_in, const int* in_sizes, int n_in,
                              void* d_out, int out_size, void* d_ws, size_t ws_size,
                              hipStream_t stream) {
    const float* emb  = (const float*)d_in[0];
    const float* W    = (const float*)d_in[1];
    const float* bias = (const float*)d_in[2];
    f4x* out = (f4x*)d_out;

    float* left  = (float*)d_ws;            // 16384 floats
    float* right = left + PB_ROWS;          // 16384 floats (128 KiB total)

    // Kernel 1: 16384 rows / 4 waves per block = 4096 blocks
    probe_dot_kernel<<<4096, 256, 0, stream>>>(emb, W, bias, left, right);

    // Kernel 2: 8*2048*2048 / 4 = 8,388,608 float4s / 256 = 32768 blocks
    probe_bcast_kernel<<<32768, 256, 0, stream>>>(left, right, out);
}